// Round 6
// baseline (413.635 us; speedup 1.0000x reference)
//
#include <hip/hip_runtime.h>
#include <hip/hip_bf16.h>
#include <math.h>

#define B_    8
#define S_    2048
#define KIN_  512
#define NIN_  4096
#define P_    2048
#define D_    1024
#define KSEL_ 256

typedef __attribute__((ext_vector_type(8))) short short8;
typedef __attribute__((ext_vector_type(4))) float f32x4;

__device__ __forceinline__ unsigned short f2bf(float f) {
    unsigned u = __float_as_uint(f);
    unsigned r = (u + 0x7fffu + ((u >> 16) & 1u)) >> 16;
    return (unsigned short)r;
}
__device__ __forceinline__ float bf2f(unsigned short h) {
    return __uint_as_float(((unsigned)h) << 16);
}
__device__ __forceinline__ float gelu_exact(float x) {
    return 0.5f * x * (1.0f + erff(x * 0.70710678118654752f));
}
__device__ __forceinline__ void gl2lds16(const void* g, void* l) {
    __builtin_amdgcn_global_load_lds(
        (const __attribute__((address_space(1))) unsigned int*)g,
        (__attribute__((address_space(3))) unsigned int*)l, 16, 0, 0);
}

// ---------------------------------------------------------------------------
// AloF fragment-swizzled layout (16 MB):
//   AloF[b][kb][sb][lane][8]: element (s,k) at b*1048576 + (k>>5)*65536
//       + (s>>4)*512 + (((k>>3)&3)*16 + (s&15))*8 + (k&7)
// A 16-row x 32-k MFMA fragment block is a contiguous 1KB chunk -> one
// coalesced global_load_dwordx4 per lane, straight into the MFMA operand.
// Ahi/Ghi/Glo stay row-major (staged via global_load_lds in gemm1).
// ---------------------------------------------------------------------------

// ---------------------------------------------------------------------------
// prep: blocks [0,1024): split A fp32 -> Ahi (row-major bf16) + AloF
//       blocks [1024,3072): one W row per block. Stage the 16KB row in LDS
//       (coalesced float4) + all 8 batches' idx (16KB); each wave gathers
//       from LDS and writes 2 batches' (Ghi,Glo) rows.
// ---------------------------------------------------------------------------
__global__ __launch_bounds__(256) void prep_kernel(
        const float* __restrict__ A, const float* __restrict__ W,
        const int* __restrict__ idx,
        unsigned short* __restrict__ Ahi, unsigned short* __restrict__ AloF,
        unsigned short* __restrict__ Ghi, unsigned short* __restrict__ Glo) {
    __shared__ float wrow_s[NIN_];      // 16KB
    __shared__ int   ibs8[B_ * KIN_];   // 16KB
    int id = blockIdx.x;
    int t  = threadIdx.x;
    if (id < 1024) {
        int b = id >> 7, rb = id & 127;
        int l = t & 63, wv = t >> 6;
        int lr = l & 15, quad = l >> 4;
        const float* src = A + ((size_t)(b * S_ + rb * 16 + lr)) * KIN_ + quad * 8;
        unsigned short* dh = Ahi + ((size_t)(b * S_ + rb * 16 + lr)) * KIN_ + quad * 8;
        unsigned short* dl = AloF + (size_t)b * 1048576 + (size_t)rb * 512 + (size_t)l * 8;
        for (int kb = wv; kb < 16; kb += 4) {
            float4 v0 = *(const float4*)(src + kb * 32);
            float4 v1 = *(const float4*)(src + kb * 32 + 4);
            float vv[8] = {v0.x, v0.y, v0.z, v0.w, v1.x, v1.y, v1.z, v1.w};
            short8 h8, l8;
#pragma unroll
            for (int jj = 0; jj < 8; jj++) {
                unsigned short h = f2bf(vv[jj]);
                h8[jj] = (short)h;
                l8[jj] = (short)f2bf(vv[jj] - bf2f(h));
            }
            *(short8*)(dh + kb * 32) = h8;
            *(short8*)(dl + (size_t)kb * 65536) = l8;
        }
    } else {
        int p = id - 1024;              // 0..2047: one W row, all 8 batches
        const float* wrow = W + (size_t)p * NIN_;
#pragma unroll
        for (int i = 0; i < 4; i++)     // 4096 floats = 1024 float4
            *(float4*)(wrow_s + (t + i * 256) * 4) =
                *(const float4*)(wrow + (t + i * 256) * 4);
#pragma unroll
        for (int i = 0; i < 16; i++)    // 8*512 ints, idx is b-major flat
            ibs8[t + i * 256] = idx[t + i * 256];
        __syncthreads();
        int wv = t >> 6, tt = t & 63;
#pragma unroll
        for (int bi = 0; bi < 2; ++bi) {
            int b = wv * 2 + bi;
            size_t o = ((size_t)b * P_ + p) * KIN_;
            const int* ib = ibs8 + b * KIN_;
            short8 h8, l8;
#pragma unroll
            for (int e = 0; e < 8; e++) {
                float v = wrow_s[ib[tt * 8 + e]];
                unsigned short h = f2bf(v);
                h8[e] = (short)h;
                l8[e] = (short)f2bf(v - bf2f(h));
            }
            *(short8*)(Ghi + o + tt * 8) = h8;
            *(short8*)(Glo + o + tt * 8) = l8;
        }
    }
}

// ---------------------------------------------------------------------------
// gemm1_score (256-squared, 8-wave, 4-phase template per m201):
// x = A*G^T (3-term split bf16 MFMA), scores += sum_s gelu(x);
// optionally (STORE_C) writes bf16 gelu(x) to C [b][s][p].
// - 256x256 tile, BK=32, 512 threads = 8 waves (2M x 4N), per-wave 128x64.
// - LDS 96KB: 2 x {Ahi 16K | Ghi 16K | Glo 16K}; AloF direct global->reg,
//   pair-rotated one phase ahead (compiler vmcnt stays counted, never 0).
// - 4 phases/K-step (mt pairs); each: {al prefetch | ds_reads | staging}
//   -> barrier -> setprio(1) -> 24 MFMA -> setprio(0) -> barrier.
//   One counted vmcnt(4) per K-step at phase 0 (drains stage(it), keeps
//   al pair + next A staging in flight). Staging spread A/G/H over ph 0/1/2.
// - Per-element accumulation order (t1,t2,t3; K ascending) identical to the
//   2-phase kernel -> bit-identical C and scores.
// - XCD swizzle: 2x2 tile clusters pinned per XCD (2MB working set < 4MB L2).
// ---------------------------------------------------------------------------
#define MFMA16(m0, A0, A1, AL0, AL1)                                                                      \
    _Pragma("unroll")                                                                                     \
    for (int nt = 0; nt < 4; nt++) {                                                                      \
        acc[m0][nt]     = __builtin_amdgcn_mfma_f32_16x16x32_bf16(A0, gh[nt], acc[m0][nt], 0, 0, 0);      \
        acc[m0][nt]     = __builtin_amdgcn_mfma_f32_16x16x32_bf16(A0, gl[nt], acc[m0][nt], 0, 0, 0);      \
        acc[m0 + 1][nt] = __builtin_amdgcn_mfma_f32_16x16x32_bf16(A1, gh[nt], acc[m0 + 1][nt], 0, 0, 0);  \
        acc[m0 + 1][nt] = __builtin_amdgcn_mfma_f32_16x16x32_bf16(A1, gl[nt], acc[m0 + 1][nt], 0, 0, 0);  \
    }                                                                                                     \
    _Pragma("unroll")                                                                                     \
    for (int nt = 0; nt < 4; nt++) {                                                                      \
        acc[m0][nt]     = __builtin_amdgcn_mfma_f32_16x16x32_bf16(AL0, gh[nt], acc[m0][nt], 0, 0, 0);     \
        acc[m0 + 1][nt] = __builtin_amdgcn_mfma_f32_16x16x32_bf16(AL1, gh[nt], acc[m0 + 1][nt], 0, 0, 0); \
    }

template <bool STORE_C>
__global__ __launch_bounds__(512, 2) void gemm1_score(
        const unsigned short* __restrict__ Ahi, const unsigned short* __restrict__ AloF,
        const unsigned short* __restrict__ Ghi, const unsigned short* __restrict__ Glo,
        float* __restrict__ scores, unsigned short* __restrict__ C) {
    __shared__ __align__(16) unsigned short lds[49152];  // 2 x 48KB buffers

    // --- XCD swizzle: 512 blocks -> (b, s0, p0), 2x2 clusters per XCD ---
    int d    = blockIdx.x;             // 0..511
    int xcd  = d & 7;
    int s2   = d >> 3;                 // 0..63
    int cid  = (s2 >> 2) * 8 + xcd;    // 0..127
    int j    = s2 & 3;
    int b    = cid >> 4;
    int rc   = cid & 15;
    int p0   = ((rc & 3) * 2 + (j & 1)) * 256;
    int s0   = ((rc >> 2) * 2 + (j >> 1)) * 256;

    const int t = threadIdx.x;
    const int w = t >> 6, l = t & 63;
    const int wm = w >> 2, wn = w & 3;  // 2 M-waves x 4 N-waves
    const int lr = l & 15, quad = l >> 4;

    // staging: 6 sweeps/K-step (Ahi x2, Ghi x2, Glo x2); 128 rows per sweep
    const int srow = t >> 2;
    const int koff = ((t & 3) ^ ((t >> 3) & 3)) * 8;   // source-side swizzle
    const size_t baseA = ((size_t)(b * S_ + s0)) * KIN_;
    const size_t baseG = ((size_t)(b * P_ + p0)) * KIN_;
    const unsigned short* pA0 = Ahi + baseA + (size_t)srow * KIN_ + koff;
    const unsigned short* pA1 = pA0 + (size_t)128 * KIN_;
    const unsigned short* pG0 = Ghi + baseG + (size_t)srow * KIN_ + koff;
    const unsigned short* pG1 = pG0 + (size_t)128 * KIN_;
    const unsigned short* pH0 = Glo + baseG + (size_t)srow * KIN_ + koff;
    const unsigned short* pH1 = pH0 + (size_t)128 * KIN_;
    const unsigned short* alB = AloF + (size_t)b * 1048576
                              + (size_t)((s0 >> 4) + wm * 8) * 512 + (size_t)l * 8;
    char* lb = (char*)lds + w * 1024;

    int ra[8], rg[4];
#pragma unroll
    for (int i = 0; i < 8; i++) {
        int row = wm * 128 + i * 16 + lr;
        ra[i] = row * 32 + (quad ^ ((row >> 1) & 3)) * 8;
    }
#pragma unroll
    for (int i = 0; i < 4; i++) {
        int row = wn * 64 + i * 16 + lr;
        rg[i] = row * 32 + (quad ^ ((row >> 1) & 3)) * 8;
    }

    f32x4 acc[8][4];
#pragma unroll
    for (int i = 0; i < 8; i++)
#pragma unroll
        for (int jj = 0; jj < 4; jj++) acc[i][jj] = (f32x4){0.f, 0.f, 0.f, 0.f};

    auto issueA = [&](int k0, int bf) {
        char* dst = lb + bf * 49152;
        gl2lds16(pA0 + k0, dst + 0);
        gl2lds16(pA1 + k0, dst + 8192);
    };
    auto issueG = [&](int k0, int bf) {
        char* dst = lb + bf * 49152;
        gl2lds16(pG0 + k0, dst + 16384);
        gl2lds16(pG1 + k0, dst + 24576);
    };
    auto issueH = [&](int k0, int bf) {
        char* dst = lb + bf * 49152;
        gl2lds16(pH0 + k0, dst + 32768);
        gl2lds16(pH1 + k0, dst + 40960);
    };

    // prologue: stage K-step 0, load al pair 0 of K-step 0
    issueA(0, 0); issueG(0, 0); issueH(0, 0);
    short8 alc0 = *(const short8*)(alB);
    short8 alc1 = *(const short8*)(alB + 512);
    short8 gh[4], gl[4];

    for (int it = 0; it < 16; ++it) {
        const unsigned short* Lb = lds + (it & 1) * 24576;
        const unsigned short* aB = alB + (size_t)it * 65536;
        const int nk  = (it + 1) * 32;
        const int nbf = (it + 1) & 1;
        const bool more = it < 15;
        short8 aln0, aln1;

        // ---- phase 0 (mt 0,1): stage A(it+1); counted vmcnt; gh/gl reads ----
        aln0 = *(const short8*)(aB + 1024);   // al pair for phase 1
        aln1 = *(const short8*)(aB + 1536);
        if (more) {
            issueA(nk, nbf);
            // keep newest 4 (aln pair + A staging), drain stage(it) + alc
            asm volatile("s_waitcnt vmcnt(4)\n\ts_barrier" ::: "memory");
        } else {
            asm volatile("s_waitcnt vmcnt(2)\n\ts_barrier" ::: "memory");
        }
        {
#pragma unroll
            for (int i = 0; i < 4; i++) {
                gh[i] = *(const short8*)(Lb + 8192 + rg[i]);
                gl[i] = *(const short8*)(Lb + 16384 + rg[i]);
            }
            short8 a0 = *(const short8*)(Lb + ra[0]);
            short8 a1 = *(const short8*)(Lb + ra[1]);
            __builtin_amdgcn_s_setprio(1);
            MFMA16(0, a0, a1, alc0, alc1)
            __builtin_amdgcn_s_setprio(0);
            asm volatile("s_barrier" ::: "memory");
        }
        alc0 = aln0; alc1 = aln1;

        // ---- phase 1 (mt 2,3): stage G(it+1) ----
        aln0 = *(const short8*)(aB + 2048);
        aln1 = *(const short8*)(aB + 2560);
        {
            short8 a0 = *(const short8*)(Lb + ra[2]);
            short8 a1 = *(const short8*)(Lb + ra[3]);
            if (more) issueG(nk, nbf);
            asm volatile("s_barrier" ::: "memory");
            __builtin_amdgcn_s_setprio(1);
            MFMA16(2, a0, a1, alc0, alc1)
            __builtin_amdgcn_s_setprio(0);
            asm volatile("s_barrier" ::: "memory");
        }
        alc0 = aln0; alc1 = aln1;

        // ---- phase 2 (mt 4,5): stage H(it+1) ----
        aln0 = *(const short8*)(aB + 3072);
        aln1 = *(const short8*)(aB + 3584);
        {
            short8 a0 = *(const short8*)(Lb + ra[4]);
            short8 a1 = *(const short8*)(Lb + ra[5]);
            if (more) issueH(nk, nbf);
            asm volatile("s_barrier" ::: "memory");
            __builtin_amdgcn_s_setprio(1);
            MFMA16(4, a0, a1, alc0, alc1)
            __builtin_amdgcn_s_setprio(0);
            asm volatile("s_barrier" ::: "memory");
        }
        alc0 = aln0; alc1 = aln1;

        // ---- phase 3 (mt 6,7): prefetch al pair 0 of it+1 ----
        if (more) {
            aln0 = *(const short8*)(aB + 65536);
            aln1 = *(const short8*)(aB + 65536 + 512);
        }
        {
            short8 a0 = *(const short8*)(Lb + ra[6]);
            short8 a1 = *(const short8*)(Lb + ra[7]);
            asm volatile("s_barrier" ::: "memory");
            __builtin_amdgcn_s_setprio(1);
            MFMA16(6, a0, a1, alc0, alc1)
            __builtin_amdgcn_s_setprio(0);
            asm volatile("s_barrier" ::: "memory");
        }
        if (more) { alc0 = aln0; alc1 = aln1; }
    }

    // Epilogue: gelu, per-column score sums, optional bf16 C tile store
    float colsum[4] = {0.f, 0.f, 0.f, 0.f};
#pragma unroll
    for (int mt = 0; mt < 8; mt++)
#pragma unroll
        for (int nt = 0; nt < 4; nt++)
#pragma unroll
            for (int r = 0; r < 4; r++) {
                float g = gelu_exact(acc[mt][nt][r]);
                colsum[nt] += g;
                acc[mt][nt][r] = g;
            }
#pragma unroll
    for (int nt = 0; nt < 4; nt++) {
        colsum[nt] += __shfl_xor(colsum[nt], 16);
        colsum[nt] += __shfl_xor(colsum[nt], 32);
    }
    if (quad == 0) {
#pragma unroll
        for (int nt = 0; nt < 4; nt++)
            atomicAdd(&scores[b * P_ + p0 + wn * 64 + nt * 16 + lr], colsum[nt]);
    }

    if (STORE_C) {
        // two 128-row halves through LDS (128x256 bf16 = 64KB <= 96KB)
#pragma unroll
        for (int h = 0; h < 2; h++) {
            __syncthreads();
            if (wm == h) {
#pragma unroll
                for (int mt = 0; mt < 8; mt++)
#pragma unroll
                    for (int nt = 0; nt < 4; nt++)
#pragma unroll
                        for (int r = 0; r < 4; r++) {
                            int row = mt * 16 + quad * 4 + r;      // 0..127
                            int col = wn * 64 + nt * 16 + lr;
                            lds[row * 256 + col] = f2bf(acc[mt][nt][r]);
                        }
            }
            __syncthreads();
            for (int i = t; i < 4096; i += 512) {
                int row = i >> 5, ch = i & 31;
                uint4 v = *(const uint4*)(lds + row * 256 + ch * 8);
                *(uint4*)(C + ((size_t)(b * S_ + s0 + h * 128 + row)) * P_ + p0 + ch * 8) = v;
            }
        }
    }
}

// ---------------------------------------------------------------------------
// top-256 of 2048 scores per batch (bitonic, desc, tie: low idx).
// Selected indices re-sorted ascending (set-invariant for the output).
// ---------------------------------------------------------------------------
__global__ __launch_bounds__(1024) void topk_kernel(const float* __restrict__ scores,
                                                    int* __restrict__ pidx) {
    __shared__ float v[2048];
    __shared__ int   ix[2048];
    int b = blockIdx.x;
    int t = threadIdx.x;
    for (int i = t; i < 2048; i += 1024) { v[i] = scores[b * 2048 + i]; ix[i] = i; }
    __syncthreads();
    for (int k = 2; k <= 2048; k <<= 1) {
        for (int j = k >> 1; j > 0; j >>= 1) {
            for (int i = t; i < 2048; i += 1024) {
                int o = i ^ j;
                if (o > i) {
                    bool desc = ((i & k) == 0);
                    float va = v[i], vb = v[o];
                    int ia = ix[i], ib = ix[o];
                    bool b_first = (vb > va) || (vb == va && ib < ia);
                    if (desc == b_first) { v[i] = vb; v[o] = va; ix[i] = ib; ix[o] = ia; }
                }
            }
            __syncthreads();
        }
    }
    // ascending re-sort of the selected 256 indices (set-invariant)
    for (int k = 2; k <= 256; k <<= 1) {
        for (int j = k >> 1; j > 0; j >>= 1) {
            if (t < 256) {
                int i = t, o = i ^ j;
                if (o > i) {
                    bool asc = ((i & k) == 0);
                    int a = ix[i], c2 = ix[o];
                    if ((a > c2) == asc) { ix[i] = c2; ix[o] = a; }
                }
            }
            __syncthreads();
        }
    }
    if (t < KSEL_) pidx[b * KSEL_ + t] = ix[t];
}

// ---------------------------------------------------------------------------
// gathers: id in [0,2048): selact[b][s][t] = C[b][s][pidx[b][t]]
//          id in [2048,2560): PselT[b][d][k] = bf16(proj[pidx[b][k]][d])
// ---------------------------------------------------------------------------
__global__ __launch_bounds__(256) void gathers_kernel(
        const unsigned short* __restrict__ C, const float* __restrict__ proj,
        const int* __restrict__ pidx,
        unsigned short* __restrict__ selact, unsigned short* __restrict__ PselT,
        int base) {
    __shared__ int pj[256];
    __shared__ unsigned short tile[64][65];
    int id = blockIdx.x + base, t = threadIdx.x;
    if (id < 2048) {
        int b = id >> 8;
        pj[t] = pidx[b * KSEL_ + t];
        __syncthreads();
        size_t r0 = (size_t)b * S_ + (id & 255) * 8;
#pragma unroll
        for (int r = 0; r < 8; ++r) {
            size_t row = r0 + r;
            selact[row * KSEL_ + t] = C[row * P_ + pj[t]];
        }
    } else {
        int g = id - 2048;
        int d0 = (g & 15) * 64, k0 = ((g >> 4) & 3) * 64, b = g >> 6;
        int tr = t >> 6;     // 0..3
        int tc = t & 63;
#pragma unroll
        for (int r = 0; r < 16; r++) {
            int kk = r * 4 + tr;
            int prow = pidx[b * KSEL_ + k0 + kk];
            tile[kk][tc] = f2bf(proj[(size_t)prow * D_ + d0 + tc]);
        }
        __syncthreads();
#pragma unroll
        for (int r = 0; r < 16; r++) {
            int dd = r * 4 + tr;
            PselT[((size_t)(b * D_ + d0 + dd)) * KSEL_ + k0 + tc] = tile[tc][dd];
        }
    }
}

// ---------------------------------------------------------------------------
// gemm1b (fallback when ws too small): recompute selected 256 columns.
// Ahi/Ghi/Glo staged (single buffer); AloF direct. 128x128 tile, 256 thr.
// ---------------------------------------------------------------------------
__global__ __launch_bounds__(256) void gemm1b_selact(
        const unsigned short* __restrict__ Ahi, const unsigned short* __restrict__ AloF,
        const unsigned short* __restrict__ Ghi, const unsigned short* __restrict__ Glo,
        const int* __restrict__ pidx, unsigned short* __restrict__ selact) {
    __shared__ __align__(16) unsigned short lds[16384];

    const int t  = threadIdx.x;
    const int b  = blockIdx.z;
    const int s0 = blockIdx.y * 128;
    const int n0 = blockIdx.x * 128;
    const int w = t >> 6, l = t & 63;
    const int wm = w & 1, wn = w >> 1;
    const int lr = l & 15, quad = l >> 4;

    const int srow = t >> 2;
    const int koff = ((t & 3) ^ ((t >> 3) & 3)) * 8;
    const size_t baseA = ((size_t)(b * S_ + s0)) * KIN_;
    const size_t offA0 = baseA + (size_t)srow * KIN_ + koff;
    const size_t offA1 = offA0 + (size_t)64 * KIN_;
    const int prow0 = pidx[b * KSEL_ + n0 + srow];
    const int prow1 = pidx[b * KSEL_ + n0 + 64 + srow];
    const size_t offG0 = ((size_t)(b * P_ + prow0)) * KIN_ + koff;
    const size_t offG1 = ((size_t)(b * P_ + prow1)) * KIN_ + koff;
    const unsigned short* alB = AloF + (size_t)b * 1048576
                              + (size_t)((s0 >> 4) + wm * 4) * 512 + (size_t)l * 8;
    char* lb = (char*)lds + w * 1024;

    int ra[4], rg[4];
#pragma unroll
    for (int i = 0; i < 4; i++) {
        int rowa = wm * 64 + i * 16 + lr;
        int rowg = wn * 64 + i * 16 + lr;
        ra[i] = rowa * 32 + (quad ^ ((rowa >> 1) & 3)) * 8;
        rg[i] = rowg * 32 + (quad ^ ((rowg >> 1) & 3)) * 8;
    }

    f32x4 acc[4][4];
#pragma unroll
    for (int i = 0; i < 4; i++)
#pragma unroll
        for (int jj = 0; jj < 4; jj++) acc[i][jj] = (f32x4){0.f, 0.f, 0.f, 0.f};

    for (int k0 = 0; k0 < KIN_; k0 += 32) {
        int kb = k0 >> 5;
        gl2lds16(Ahi + offA0 + k0, lb + 0);
        gl2lds16(Ahi + offA1 + k0, lb + 4096);
        gl2lds16(Ghi + offG0 + k0, lb + 8192);
        gl2lds16(Ghi + offG1 + k0, lb + 12288);
        gl2lds16(Glo + offG0 + k0, lb + 16384);
        gl2lds16(Glo + offG1 + k0, lb + 20480);
        short8 alc[4];
#pragma unroll
        for (int i = 0; i < 4; i++)
            alc[i] = *(const short8*)(alB + (size_t)kb * 65536 + i * 512);
        __syncthreads();

        short8 gh[4], gl8[4];
#pragma unroll
        for (int i = 0; i < 4; i++) {
            gh[i]  = *(const short8*)(lds + 4096 + rg[i]);
            gl8[i] = *(const short8*)(lds + 8192 + rg[i]);
        }
#pragma unroll
        for (int mt = 0; mt < 4; mt++) {
            short8 ah = *(const short8*)(lds + ra[mt]);
#pragma unroll
            for (int nt = 0; nt < 4; nt++) {
                acc[mt][nt] = __builtin_amdgcn_mfma_f32_16x16x32_bf16(ah,      gh[nt],  acc[mt][nt], 0, 0, 0);
                acc[mt][nt] = __builtin_amdgcn_mfma_f32_16x16x32_bf16(ah,      gl8[nt], acc[mt][nt], 0, 0, 0);
                acc[mt][nt] = __builtin_amdgcn_mfma_f32_16x16x32_bf16(alc[mt], gh[nt],  acc[mt][nt], 0, 0, 0);
            }
        }
        __syncthreads();
    }

#pragma unroll
    for (int mt = 0; mt < 4; mt++)
#pragma unroll
        for (int nt = 0; nt < 4; nt++)
#pragma unroll
            for (int r = 0; r < 4; r++) {
                int row = wm * 64 + mt * 16 + quad * 4 + r;
                int col = wn * 64 + nt * 16 + lr;
                lds[row * 128 + col] = f2bf(gelu_exact(acc[mt][nt][r]));
            }
    __syncthreads();
    for (int i = t; i < 2048; i += 256) {
        int row = i >> 4, ch = i & 15;
        uint4 v = *(const uint4*)(lds + row * 128 + ch * 8);
        *(uint4*)(selact + ((size_t)(b * S_ + s0 + row)) * KSEL_ + n0 + ch * 8) = v;
    }
}

// ---------------------------------------------------------------------------
// gemm2: out[b][s][d] = sum_k selact[b][s][k] * PselT[b][d][k]  (bf16 MFMA)
// dbuf LDS + raw vmcnt(4)/s_barrier pipeline; XOR source+read swizzle.
// ---------------------------------------------------------------------------
__global__ __launch_bounds__(256) void gemm2_mfma(
        const unsigned short* __restrict__ selact,
        const unsigned short* __restrict__ PselT,
        float* __restrict__ out) {
    __shared__ __align__(16) unsigned short lds[16384];  // 2 x 16KB buffers

    const int t  = threadIdx.x;
    const int b  = blockIdx.z;
    const int s0 = blockIdx.y * 128;
    const int d0 = blockIdx.x * 128;
    const int w = t >> 6, l = t & 63;
    const int wm = w & 1, wn = w >> 1;
    const int lr = l & 15, quad = l >> 4;

    const int srow = t >> 2;
    const int koff = ((t & 3) ^ ((t >> 3) & 3)) * 8;
    const unsigned short* pA0 = selact + ((size_t)(b * S_ + s0 + srow)) * KSEL_ + koff;
    const unsigned short* pA1 = pA0 + (size_t)64 * KSEL_;
    const unsigned short* pB0 = PselT + ((size_t)(b * D_ + d0 + srow)) * KSEL_ + koff;
    const unsigned short* pB1 = pB0 + (size_t)64 * KSEL_;
    char* lb = (char*)lds + w * 1024;

    int ra[4], rg[4];
#pragma unroll
    for (int i = 0; i < 4; i++) {
        int rowa = wm * 64 + i * 16 + lr;
        int rowg = wn * 64 + i * 16 + lr;
        ra[i] = rowa * 32 + (quad ^ ((rowa >> 1) & 3)) * 8;
        rg[i] = rowg * 32 + (quad ^ ((rowg >> 1) & 3)) * 8;
    }

    f32x4 acc[4][4];
#pragma unroll
    for (int i = 0; i < 4; i++)
#pragma unroll
        for (int jj = 0; jj < 4; jj++) acc[i][jj] = (f32x4){0.f, 0.f, 0.f, 0.f};

    auto issue = [&](int k0, int buf) {
        char* dst = lb + buf * 16384;
        gl2lds16(pA0 + k0, dst + 0);
        gl2lds16(pA1 + k0, dst + 4096);
        gl2lds16(pB0 + k0, dst + 8192);
        gl2lds16(pB1 + k0, dst + 12288);
    };

    issue(0, 0);
    for (int it = 0; it < KSEL_ / 32; ++it) {
        if (it + 1 < KSEL_ / 32) {
            issue((it + 1) * 32, (it + 1) & 1);
            asm volatile("s_waitcnt vmcnt(4)\n\ts_barrier" ::: "memory");
        } else {
            asm volatile("s_waitcnt vmcnt(0)\n\ts_barrier" ::: "memory");
        }
        const unsigned short* Lb = lds + (it & 1) * 8192;

        short8 af[4], bf[4];
#pragma unroll
        for (int i = 0; i < 4; i++) {
            af[i] = *(const short8*)(Lb + ra[i]);
            bf[i] = *(const short8*)(Lb + 4096 + rg[i]);
        }
#pragma unroll
        for (int mt = 0; mt < 4; mt++)
#pragma unroll
            for (int nt = 0; nt < 4; nt++)
                acc[mt][nt] = __builtin_amdgcn_mfma_f32_16x16x32_bf16(af[mt], bf[nt], acc[mt][nt], 0, 0, 0);
        asm volatile("s_barrier" ::: "memory");
    }

#pragma unroll
    for (int mt = 0; mt < 4; mt++)
#pragma unroll
        for (int nt = 0; nt < 4; nt++)
#pragma unroll
            for (int r = 0; r < 4; r++)
                out[((size_t)(b * S_ + s0 + wm * 64 + mt * 16 + quad * 4 + r)) * D_
                    + d0 + wn * 64 + nt * 16 + lr] = acc[mt][nt][r];
}

// ---------------------------------------------------------------------------
// Workspace layout (bytes):
//   Ahi/AloF/Ghi/Glo bf16 @ 0..67108863   (4 x 16,777,216; AloF frag-swizzled)
//   scores fp32           @ 67,108,864    (65,536)
//   pidx   int            @ 67,174,400    (8,192)
//   selact bf16           @ 67,182,592    (8,388,608)
//   PselT  bf16           @ 75,571,200    (4,194,304)      -> 79,765,504 (base)
//   C      bf16 [8][2048][2048] @ 79,765,504 (67,108,864)  -> 146,874,368 (big)
// ---------------------------------------------------------------------------
extern "C" void kernel_launch(void* const* d_in, const int* in_sizes, int n_in,
                              void* d_out, int out_size, void* d_ws, size_t ws_size,
                              hipStream_t stream) {
    (void)in_sizes; (void)n_in; (void)out_size;
    const float* act  = (const float*)d_in[0];
    const int*   idx  = (const int*)d_in[1];
    const float* W    = (const float*)d_in[3];
    const float* proj = (const float*)d_in[4];
    float*       out  = (float*)d_out;

    char* ws = (char*)d_ws;
    unsigned short* Ahi    = (unsigned short*)(ws + 0);
    unsigned short* AloF   = (unsigned short*)(ws + 16777216);
    unsigned short* Ghi    = (unsigned short*)(ws + 33554432);
    unsigned short* Glo    = (unsigned short*)(ws + 50331648);
    float*          scores = (float*)(ws + 67108864);
    int*            pidx   = (int*)(ws + 67174400);
    unsigned short* selact = (unsigned short*)(ws + 67182592);
    unsigned short* PselT  = (unsigned short*)(ws + 75571200);
    unsigned short* Cbf    = (unsigned short*)(ws + 79765504);
    const bool big = ws_size >= 146874368ull;

    hipMemsetAsync(scores, 0, B_ * P_ * sizeof(float), stream);

    prep_kernel<<<dim3(1024 + P_), 256, 0, stream>>>(act, W, idx, Ahi, AloF, Ghi, Glo);

    if (big) {
        gemm1_score<true><<<dim3(512), 512, 0, stream>>>(Ahi, AloF, Ghi, Glo, scores, Cbf);
        topk_kernel<<<dim3(B_), 1024, 0, stream>>>(scores, pidx);
        gathers_kernel<<<dim3(2048 + 512), 256, 0, stream>>>(Cbf, proj, pidx, selact, PselT, 0);
    } else {
        gemm1_score<false><<<dim3(512), 512, 0, stream>>>(Ahi, AloF, Ghi, Glo, scores, nullptr);
        topk_kernel<<<dim3(B_), 1024, 0, stream>>>(scores, pidx);
        gemm1b_selact<<<dim3(KSEL_ / 128, S_ / 128, B_), 256, 0, stream>>>(
            Ahi, AloF, Ghi, Glo, pidx, selact);
        gathers_kernel<<<dim3(512), 256, 0, stream>>>(Cbf, proj, pidx, selact, PselT, 2048);
    }
    gemm2_mfma<<<dim3(D_ / 128, S_ / 128, B_), 256, 0, stream>>>(selact, PselT, out);
}

// Round 7
// 352.619 us; speedup vs baseline: 1.1730x; 1.1730x over previous
//
#include <hip/hip_runtime.h>
#include <hip/hip_bf16.h>
#include <math.h>

#define B_    8
#define S_    2048
#define KIN_  512
#define NIN_  4096
#define P_    2048
#define D_    1024
#define KSEL_ 256

typedef __attribute__((ext_vector_type(8))) short short8;
typedef __attribute__((ext_vector_type(4))) float f32x4;

__device__ __forceinline__ unsigned short f2bf(float f) {
    unsigned u = __float_as_uint(f);
    unsigned r = (u + 0x7fffu + ((u >> 16) & 1u)) >> 16;
    return (unsigned short)r;
}
__device__ __forceinline__ float bf2f(unsigned short h) {
    return __uint_as_float(((unsigned)h) << 16);
}
__device__ __forceinline__ float gelu_exact(float x) {
    return 0.5f * x * (1.0f + erff(x * 0.70710678118654752f));
}
__device__ __forceinline__ void gl2lds16(const void* g, void* l) {
    __builtin_amdgcn_global_load_lds(
        (const __attribute__((address_space(1))) unsigned int*)g,
        (__attribute__((address_space(3))) unsigned int*)l, 16, 0, 0);
}

// ---------------------------------------------------------------------------
// AloF fragment-swizzled layout (16 MB):
//   AloF[b][kb][sb][lane][8]: element (s,k) at b*1048576 + (k>>5)*65536
//       + (s>>4)*512 + (((k>>3)&3)*16 + (s&15))*8 + (k&7)
// A 16-row x 32-k MFMA fragment block is a contiguous 1KB chunk -> one
// coalesced global_load_dwordx4 per lane, straight into the MFMA operand.
// Ahi/Ghi/Glo stay row-major (staged via global_load_lds in gemm1).
// ---------------------------------------------------------------------------

// ---------------------------------------------------------------------------
// prep: blocks [0,1024): split A fp32 -> Ahi (row-major bf16) + AloF
//       blocks [1024,3072): one W row per block. Stage the 16KB row in LDS
//       (coalesced float4) + all 8 batches' idx (16KB); each wave gathers
//       from LDS and writes 2 batches' (Ghi,Glo) rows.
// ---------------------------------------------------------------------------
__global__ __launch_bounds__(256) void prep_kernel(
        const float* __restrict__ A, const float* __restrict__ W,
        const int* __restrict__ idx,
        unsigned short* __restrict__ Ahi, unsigned short* __restrict__ AloF,
        unsigned short* __restrict__ Ghi, unsigned short* __restrict__ Glo) {
    __shared__ float wrow_s[NIN_];      // 16KB
    __shared__ int   ibs8[B_ * KIN_];   // 16KB
    int id = blockIdx.x;
    int t  = threadIdx.x;
    if (id < 1024) {
        int b = id >> 7, rb = id & 127;
        int l = t & 63, wv = t >> 6;
        int lr = l & 15, quad = l >> 4;
        const float* src = A + ((size_t)(b * S_ + rb * 16 + lr)) * KIN_ + quad * 8;
        unsigned short* dh = Ahi + ((size_t)(b * S_ + rb * 16 + lr)) * KIN_ + quad * 8;
        unsigned short* dl = AloF + (size_t)b * 1048576 + (size_t)rb * 512 + (size_t)l * 8;
        for (int kb = wv; kb < 16; kb += 4) {
            float4 v0 = *(const float4*)(src + kb * 32);
            float4 v1 = *(const float4*)(src + kb * 32 + 4);
            float vv[8] = {v0.x, v0.y, v0.z, v0.w, v1.x, v1.y, v1.z, v1.w};
            short8 h8, l8;
#pragma unroll
            for (int jj = 0; jj < 8; jj++) {
                unsigned short h = f2bf(vv[jj]);
                h8[jj] = (short)h;
                l8[jj] = (short)f2bf(vv[jj] - bf2f(h));
            }
            *(short8*)(dh + kb * 32) = h8;
            *(short8*)(dl + (size_t)kb * 65536) = l8;
        }
    } else {
        int p = id - 1024;              // 0..2047: one W row, all 8 batches
        const float* wrow = W + (size_t)p * NIN_;
#pragma unroll
        for (int i = 0; i < 4; i++)     // 4096 floats = 1024 float4
            *(float4*)(wrow_s + (t + i * 256) * 4) =
                *(const float4*)(wrow + (t + i * 256) * 4);
#pragma unroll
        for (int i = 0; i < 16; i++)    // 8*512 ints, idx is b-major flat
            ibs8[t + i * 256] = idx[t + i * 256];
        __syncthreads();
        int wv = t >> 6, tt = t & 63;
#pragma unroll
        for (int bi = 0; bi < 2; ++bi) {
            int b = wv * 2 + bi;
            size_t o = ((size_t)b * P_ + p) * KIN_;
            const int* ib = ibs8 + b * KIN_;
            short8 h8, l8;
#pragma unroll
            for (int e = 0; e < 8; e++) {
                float v = wrow_s[ib[tt * 8 + e]];
                unsigned short h = f2bf(v);
                h8[e] = (short)h;
                l8[e] = (short)f2bf(v - bf2f(h));
            }
            *(short8*)(Ghi + o + tt * 8) = h8;
            *(short8*)(Glo + o + tt * 8) = l8;
        }
    }
}

// ---------------------------------------------------------------------------
// gemm1_score: x = A*G^T (3-term split bf16 MFMA), scores += sum_s gelu(x).
// Optionally (STORE_C) writes bf16 gelu(x) to C [b][s][p].
// 128x128 tile, BK=32. LDS stages Ahi/Ghi/Glo (2 x 24KB dbuf -> 48KB,
// 3 blocks/CU at ~164 total regs); AloF fragments DOUBLE-BUFFERED in regs:
// aln(it+1) prefetched during it's MFMA phase (full iteration of latency
// cover vs the old same-iteration load). Source+read XOR swizzle kills the
// ds_read_b128 bank conflicts; epilogue tile padded to 136-short rows.
// vmcnt(10) = drains stage(it); keeps aln(4) + stage(it+1)(6) in flight.
// Block swizzle: 4x4 (p,s)-tile clusters pinned to one XCD.
// NOTE (R2 lesson): do NOT raise min-waves to 4 — 64 arch VGPRs starve the
// direct-load pipeline. NOTE (R6 lesson): the 256²/8-wave deep-pipeline port
// collapses to 1 block/CU (acc=128 AGPR) and loses; don't retry without a
// fundamentally smaller accumulator.
// ---------------------------------------------------------------------------
template <bool STORE_C>
__global__ __launch_bounds__(256, 3) void gemm1_score(
        const unsigned short* __restrict__ Ahi, const unsigned short* __restrict__ AloF,
        const unsigned short* __restrict__ Ghi, const unsigned short* __restrict__ Glo,
        float* __restrict__ scores, unsigned short* __restrict__ C) {
    __shared__ __align__(16) unsigned short lds[24576];  // 2 x 24KB buffers

    // --- XCD cluster swizzle ---
    int d    = blockIdx.x;             // 0..2047
    int xcd  = d & 7;
    int slot = d >> 3;                 // 0..255
    int c    = (slot >> 4) * 8 + xcd;  // cluster 0..127
    int j    = slot & 15;              // position in 4x4 cluster
    int b    = c >> 4;
    int rc   = c & 15;
    int p0   = ((rc & 3) * 4 + (j & 3)) * 128;
    int s0   = ((rc >> 2) * 4 + (j >> 2)) * 128;

    const int t  = threadIdx.x;
    const int w = t >> 6, l = t & 63;
    const int wm = w & 1, wn = w >> 1;
    const int lr = l & 15, quad = l >> 4;

    const int srow = t >> 2;
    const int koff = ((t & 3) ^ ((t >> 3) & 3)) * 8;   // source-side swizzle
    const size_t baseA = ((size_t)(b * S_ + s0)) * KIN_;
    const size_t baseG = ((size_t)(b * P_ + p0)) * KIN_;
    const unsigned short* pA0 = Ahi + baseA + (size_t)srow * KIN_ + koff;
    const unsigned short* pA1 = pA0 + (size_t)64 * KIN_;
    const unsigned short* pG0 = Ghi + baseG + (size_t)srow * KIN_ + koff;
    const unsigned short* pG1 = pG0 + (size_t)64 * KIN_;
    const unsigned short* pH0 = Glo + baseG + (size_t)srow * KIN_ + koff;
    const unsigned short* pH1 = pH0 + (size_t)64 * KIN_;
    const unsigned short* alB = AloF + (size_t)b * 1048576
                              + (size_t)((s0 >> 4) + wm * 4) * 512 + (size_t)l * 8;
    char* lb = (char*)lds + w * 1024;

    int ra[4], rg[4];
#pragma unroll
    for (int i = 0; i < 4; i++) {
        int rowa = wm * 64 + i * 16 + lr;
        int rowg = wn * 64 + i * 16 + lr;
        ra[i] = rowa * 32 + (quad ^ ((rowa >> 1) & 3)) * 8;
        rg[i] = rowg * 32 + (quad ^ ((rowg >> 1) & 3)) * 8;
    }

    f32x4 acc[4][4];
#pragma unroll
    for (int i = 0; i < 4; i++)
#pragma unroll
        for (int jj = 0; jj < 4; jj++) acc[i][jj] = (f32x4){0.f, 0.f, 0.f, 0.f};

    auto issue = [&](int k0, int buf) {
        char* dst = lb + buf * 24576;
        gl2lds16(pA0 + k0, dst + 0);
        gl2lds16(pA1 + k0, dst + 4096);
        gl2lds16(pG0 + k0, dst + 8192);
        gl2lds16(pG1 + k0, dst + 12288);
        gl2lds16(pH0 + k0, dst + 16384);
        gl2lds16(pH1 + k0, dst + 20480);
    };

    issue(0, 0);
    short8 alc[4], aln[4];
#pragma unroll
    for (int i = 0; i < 4; i++)
        alc[i] = *(const short8*)(alB + i * 512);

    for (int it = 0; it < KIN_ / 32; ++it) {
        const bool more = it + 1 < KIN_ / 32;
        if (more) {
            issue((it + 1) * 32, (it + 1) & 1);
            // outstanding: stage(it)[6] + alc(it)[4, issued iter it-1] +
            // stage(it+1)[6]; keep newest 10, drain stage(it).
            asm volatile("s_waitcnt vmcnt(10)\n\ts_barrier" ::: "memory");
        } else {
            asm volatile("s_waitcnt vmcnt(0)\n\ts_barrier" ::: "memory");
        }
        const unsigned short* Lb = lds + (it & 1) * 12288;

        short8 gh[4], gl8[4];
#pragma unroll
        for (int i = 0; i < 4; i++) {
            gh[i]  = *(const short8*)(Lb + 4096 + rg[i]);
            gl8[i] = *(const short8*)(Lb + 8192 + rg[i]);
        }
        // prefetch next iteration's al fragments; they complete under this
        // iteration's MFMA phase (full-iteration latency cover).
        if (more) {
#pragma unroll
            for (int i = 0; i < 4; i++)
                aln[i] = *(const short8*)(alB + (size_t)(it + 1) * 65536 + i * 512);
        }
#pragma unroll
        for (int mt = 0; mt < 4; mt++) {
            short8 ah = *(const short8*)(Lb + ra[mt]);
#pragma unroll
            for (int nt = 0; nt < 4; nt++) {
                acc[mt][nt] = __builtin_amdgcn_mfma_f32_16x16x32_bf16(ah,      gh[nt],  acc[mt][nt], 0, 0, 0);
                acc[mt][nt] = __builtin_amdgcn_mfma_f32_16x16x32_bf16(ah,      gl8[nt], acc[mt][nt], 0, 0, 0);
                acc[mt][nt] = __builtin_amdgcn_mfma_f32_16x16x32_bf16(alc[mt], gh[nt],  acc[mt][nt], 0, 0, 0);
            }
        }
        asm volatile("s_barrier" ::: "memory");
        if (more) {
#pragma unroll
            for (int i = 0; i < 4; i++) alc[i] = aln[i];
        }
    }

    // Epilogue: gelu, per-column score sums, optional bf16 C tile store
    float colsum[4] = {0.f, 0.f, 0.f, 0.f};
#pragma unroll
    for (int mt = 0; mt < 4; mt++)
#pragma unroll
        for (int nt = 0; nt < 4; nt++)
#pragma unroll
            for (int r = 0; r < 4; r++) {
                float g = gelu_exact(acc[mt][nt][r]);
                colsum[nt] += g;
                acc[mt][nt][r] = g;
            }
#pragma unroll
    for (int nt = 0; nt < 4; nt++) {
        colsum[nt] += __shfl_xor(colsum[nt], 16);
        colsum[nt] += __shfl_xor(colsum[nt], 32);
    }
    if (quad == 0) {
#pragma unroll
        for (int nt = 0; nt < 4; nt++)
            atomicAdd(&scores[b * P_ + p0 + wn * 64 + nt * 16 + lr], colsum[nt]);
    }

    if (STORE_C) {
        // padded tile: 136-short rows (272B, 16B-aligned) -> banks spread
#pragma unroll
        for (int mt = 0; mt < 4; mt++)
#pragma unroll
            for (int nt = 0; nt < 4; nt++)
#pragma unroll
                for (int r = 0; r < 4; r++) {
                    int row = wm * 64 + mt * 16 + quad * 4 + r;
                    int col = wn * 64 + nt * 16 + lr;
                    lds[row * 136 + col] = f2bf(acc[mt][nt][r]);
                }
        __syncthreads();
        for (int i = t; i < 2048; i += 256) {
            int row = i >> 4, ch = i & 15;
            uint4 v = *(const uint4*)(lds + row * 136 + ch * 8);
            *(uint4*)(C + ((size_t)(b * S_ + s0 + row)) * P_ + p0 + ch * 8) = v;
        }
    }
}

// ---------------------------------------------------------------------------
// top-256 of 2048 scores per batch (bitonic, desc, tie: low idx).
// Selected indices re-sorted ascending (set-invariant for the output).
// ---------------------------------------------------------------------------
__global__ __launch_bounds__(1024) void topk_kernel(const float* __restrict__ scores,
                                                    int* __restrict__ pidx) {
    __shared__ float v[2048];
    __shared__ int   ix[2048];
    int b = blockIdx.x;
    int t = threadIdx.x;
    for (int i = t; i < 2048; i += 1024) { v[i] = scores[b * 2048 + i]; ix[i] = i; }
    __syncthreads();
    for (int k = 2; k <= 2048; k <<= 1) {
        for (int j = k >> 1; j > 0; j >>= 1) {
            for (int i = t; i < 2048; i += 1024) {
                int o = i ^ j;
                if (o > i) {
                    bool desc = ((i & k) == 0);
                    float va = v[i], vb = v[o];
                    int ia = ix[i], ib = ix[o];
                    bool b_first = (vb > va) || (vb == va && ib < ia);
                    if (desc == b_first) { v[i] = vb; v[o] = va; ix[i] = ib; ix[o] = ia; }
                }
            }
            __syncthreads();
        }
    }
    // ascending re-sort of the selected 256 indices (set-invariant)
    for (int k = 2; k <= 256; k <<= 1) {
        for (int j = k >> 1; j > 0; j >>= 1) {
            if (t < 256) {
                int i = t, o = i ^ j;
                if (o > i) {
                    bool asc = ((i & k) == 0);
                    int a = ix[i], c2 = ix[o];
                    if ((a > c2) == asc) { ix[i] = c2; ix[o] = a; }
                }
            }
            __syncthreads();
        }
    }
    if (t < KSEL_) pidx[b * KSEL_ + t] = ix[t];
}

// ---------------------------------------------------------------------------
// gathers: id in [0,2048): selact[b][s][t] = C[b][s][pidx[b][t]]
//          id in [2048,2560): PselT[b][d][k] = bf16(proj[pidx[b][k]][d])
// ---------------------------------------------------------------------------
__global__ __launch_bounds__(256) void gathers_kernel(
        const unsigned short* __restrict__ C, const float* __restrict__ proj,
        const int* __restrict__ pidx,
        unsigned short* __restrict__ selact, unsigned short* __restrict__ PselT,
        int base) {
    __shared__ int pj[256];
    __shared__ unsigned short tile[64][65];
    int id = blockIdx.x + base, t = threadIdx.x;
    if (id < 2048) {
        int b = id >> 8;
        pj[t] = pidx[b * KSEL_ + t];
        __syncthreads();
        size_t r0 = (size_t)b * S_ + (id & 255) * 8;
#pragma unroll
        for (int r = 0; r < 8; ++r) {
            size_t row = r0 + r;
            selact[row * KSEL_ + t] = C[row * P_ + pj[t]];
        }
    } else {
        int g = id - 2048;
        int d0 = (g & 15) * 64, k0 = ((g >> 4) & 3) * 64, b = g >> 6;
        int tr = t >> 6;     // 0..3
        int tc = t & 63;
#pragma unroll
        for (int r = 0; r < 16; r++) {
            int kk = r * 4 + tr;
            int prow = pidx[b * KSEL_ + k0 + kk];
            tile[kk][tc] = f2bf(proj[(size_t)prow * D_ + d0 + tc]);
        }
        __syncthreads();
#pragma unroll
        for (int r = 0; r < 16; r++) {
            int dd = r * 4 + tr;
            PselT[((size_t)(b * D_ + d0 + dd)) * KSEL_ + k0 + tc] = tile[tc][dd];
        }
    }
}

// ---------------------------------------------------------------------------
// gemm1b (fallback when ws too small): recompute selected 256 columns.
// Ahi/Ghi/Glo staged (single buffer); AloF direct.
// ---------------------------------------------------------------------------
__global__ __launch_bounds__(256) void gemm1b_selact(
        const unsigned short* __restrict__ Ahi, const unsigned short* __restrict__ AloF,
        const unsigned short* __restrict__ Ghi, const unsigned short* __restrict__ Glo,
        const int* __restrict__ pidx, unsigned short* __restrict__ selact) {
    __shared__ __align__(16) unsigned short lds[16384];

    const int t  = threadIdx.x;
    const int b  = blockIdx.z;
    const int s0 = blockIdx.y * 128;
    const int n0 = blockIdx.x * 128;
    const int w = t >> 6, l = t & 63;
    const int wm = w & 1, wn = w >> 1;
    const int lr = l & 15, quad = l >> 4;

    const int srow = t >> 2;
    const int koff = ((t & 3) ^ ((t >> 3) & 3)) * 8;
    const size_t baseA = ((size_t)(b * S_ + s0)) * KIN_;
    const size_t offA0 = baseA + (size_t)srow * KIN_ + koff;
    const size_t offA1 = offA0 + (size_t)64 * KIN_;
    const int prow0 = pidx[b * KSEL_ + n0 + srow];
    const int prow1 = pidx[b * KSEL_ + n0 + 64 + srow];
    const size_t offG0 = ((size_t)(b * P_ + prow0)) * KIN_ + koff;
    const size_t offG1 = ((size_t)(b * P_ + prow1)) * KIN_ + koff;
    const unsigned short* alB = AloF + (size_t)b * 1048576
                              + (size_t)((s0 >> 4) + wm * 4) * 512 + (size_t)l * 8;
    char* lb = (char*)lds + w * 1024;

    int ra[4], rg[4];
#pragma unroll
    for (int i = 0; i < 4; i++) {
        int rowa = wm * 64 + i * 16 + lr;
        int rowg = wn * 64 + i * 16 + lr;
        ra[i] = rowa * 32 + (quad ^ ((rowa >> 1) & 3)) * 8;
        rg[i] = rowg * 32 + (quad ^ ((rowg >> 1) & 3)) * 8;
    }

    f32x4 acc[4][4];
#pragma unroll
    for (int i = 0; i < 4; i++)
#pragma unroll
        for (int jj = 0; jj < 4; jj++) acc[i][jj] = (f32x4){0.f, 0.f, 0.f, 0.f};

    for (int k0 = 0; k0 < KIN_; k0 += 32) {
        int kb = k0 >> 5;
        gl2lds16(Ahi + offA0 + k0, lb + 0);
        gl2lds16(Ahi + offA1 + k0, lb + 4096);
        gl2lds16(Ghi + offG0 + k0, lb + 8192);
        gl2lds16(Ghi + offG1 + k0, lb + 12288);
        gl2lds16(Glo + offG0 + k0, lb + 16384);
        gl2lds16(Glo + offG1 + k0, lb + 20480);
        short8 alc[4];
#pragma unroll
        for (int i = 0; i < 4; i++)
            alc[i] = *(const short8*)(alB + (size_t)kb * 65536 + i * 512);
        __syncthreads();

        short8 gh[4], gl8[4];
#pragma unroll
        for (int i = 0; i < 4; i++) {
            gh[i]  = *(const short8*)(lds + 4096 + rg[i]);
            gl8[i] = *(const short8*)(lds + 8192 + rg[i]);
        }
#pragma unroll
        for (int mt = 0; mt < 4; mt++) {
            short8 ah = *(const short8*)(lds + ra[mt]);
#pragma unroll
            for (int nt = 0; nt < 4; nt++) {
                acc[mt][nt] = __builtin_amdgcn_mfma_f32_16x16x32_bf16(ah,      gh[nt],  acc[mt][nt], 0, 0, 0);
                acc[mt][nt] = __builtin_amdgcn_mfma_f32_16x16x32_bf16(ah,      gl8[nt], acc[mt][nt], 0, 0, 0);
                acc[mt][nt] = __builtin_amdgcn_mfma_f32_16x16x32_bf16(alc[mt], gh[nt],  acc[mt][nt], 0, 0, 0);
            }
        }
        __syncthreads();
    }

#pragma unroll
    for (int mt = 0; mt < 4; mt++)
#pragma unroll
        for (int nt = 0; nt < 4; nt++)
#pragma unroll
            for (int r = 0; r < 4; r++) {
                int row = wm * 64 + mt * 16 + quad * 4 + r;
                int col = wn * 64 + nt * 16 + lr;
                lds[row * 128 + col] = f2bf(gelu_exact(acc[mt][nt][r]));
            }
    __syncthreads();
    for (int i = t; i < 2048; i += 256) {
        int row = i >> 4, ch = i & 15;
        uint4 v = *(const uint4*)(lds + row * 128 + ch * 8);
        *(uint4*)(selact + ((size_t)(b * S_ + s0 + row)) * KSEL_ + n0 + ch * 8) = v;
    }
}

// ---------------------------------------------------------------------------
// gemm2: out[b][s][d] = sum_k selact[b][s][k] * PselT[b][d][k]  (bf16 MFMA)
// dbuf LDS + raw vmcnt(4)/s_barrier pipeline; XOR source+read swizzle.
// ---------------------------------------------------------------------------
__global__ __launch_bounds__(256) void gemm2_mfma(
        const unsigned short* __restrict__ selact,
        const unsigned short* __restrict__ PselT,
        float* __restrict__ out) {
    __shared__ __align__(16) unsigned short lds[16384];  // 2 x 16KB buffers

    const int t  = threadIdx.x;
    const int b  = blockIdx.z;
    const int s0 = blockIdx.y * 128;
    const int d0 = blockIdx.x * 128;
    const int w = t >> 6, l = t & 63;
    const int wm = w & 1, wn = w >> 1;
    const int lr = l & 15, quad = l >> 4;

    const int srow = t >> 2;
    const int koff = ((t & 3) ^ ((t >> 3) & 3)) * 8;
    const unsigned short* pA0 = selact + ((size_t)(b * S_ + s0 + srow)) * KSEL_ + koff;
    const unsigned short* pA1 = pA0 + (size_t)64 * KSEL_;
    const unsigned short* pB0 = PselT + ((size_t)(b * D_ + d0 + srow)) * KSEL_ + koff;
    const unsigned short* pB1 = pB0 + (size_t)64 * KSEL_;
    char* lb = (char*)lds + w * 1024;

    int ra[4], rg[4];
#pragma unroll
    for (int i = 0; i < 4; i++) {
        int rowa = wm * 64 + i * 16 + lr;
        int rowg = wn * 64 + i * 16 + lr;
        ra[i] = rowa * 32 + (quad ^ ((rowa >> 1) & 3)) * 8;
        rg[i] = rowg * 32 + (quad ^ ((rowg >> 1) & 3)) * 8;
    }

    f32x4 acc[4][4];
#pragma unroll
    for (int i = 0; i < 4; i++)
#pragma unroll
        for (int jj = 0; jj < 4; jj++) acc[i][jj] = (f32x4){0.f, 0.f, 0.f, 0.f};

    auto issue = [&](int k0, int buf) {
        char* dst = lb + buf * 16384;
        gl2lds16(pA0 + k0, dst + 0);
        gl2lds16(pA1 + k0, dst + 4096);
        gl2lds16(pB0 + k0, dst + 8192);
        gl2lds16(pB1 + k0, dst + 12288);
    };

    issue(0, 0);
    for (int it = 0; it < KSEL_ / 32; ++it) {
        if (it + 1 < KSEL_ / 32) {
            issue((it + 1) * 32, (it + 1) & 1);
            asm volatile("s_waitcnt vmcnt(4)\n\ts_barrier" ::: "memory");
        } else {
            asm volatile("s_waitcnt vmcnt(0)\n\ts_barrier" ::: "memory");
        }
        const unsigned short* Lb = lds + (it & 1) * 8192;

        short8 af[4], bf[4];
#pragma unroll
        for (int i = 0; i < 4; i++) {
            af[i] = *(const short8*)(Lb + ra[i]);
            bf[i] = *(const short8*)(Lb + 4096 + rg[i]);
        }
#pragma unroll
        for (int mt = 0; mt < 4; mt++)
#pragma unroll
            for (int nt = 0; nt < 4; nt++)
                acc[mt][nt] = __builtin_amdgcn_mfma_f32_16x16x32_bf16(af[mt], bf[nt], acc[mt][nt], 0, 0, 0);
        asm volatile("s_barrier" ::: "memory");
    }

#pragma unroll
    for (int mt = 0; mt < 4; mt++)
#pragma unroll
        for (int nt = 0; nt < 4; nt++)
#pragma unroll
            for (int r = 0; r < 4; r++)
                out[((size_t)(b * S_ + s0 + wm * 64 + mt * 16 + quad * 4 + r)) * D_
                    + d0 + wn * 64 + nt * 16 + lr] = acc[mt][nt][r];
}

// ---------------------------------------------------------------------------
// Workspace layout (bytes):
//   Ahi/AloF/Ghi/Glo bf16 @ 0..67108863   (4 x 16,777,216; AloF frag-swizzled)
//   scores fp32           @ 67,108,864    (65,536)
//   pidx   int            @ 67,174,400    (8,192)
//   selact bf16           @ 67,182,592    (8,388,608)
//   PselT  bf16           @ 75,571,200    (4,194,304)      -> 79,765,504 (base)
//   C      bf16 [8][2048][2048] @ 79,765,504 (67,108,864)  -> 146,874,368 (big)
// ---------------------------------------------------------------------------
extern "C" void kernel_launch(void* const* d_in, const int* in_sizes, int n_in,
                              void* d_out, int out_size, void* d_ws, size_t ws_size,
                              hipStream_t stream) {
    (void)in_sizes; (void)n_in; (void)out_size;
    const float* act  = (const float*)d_in[0];
    const int*   idx  = (const int*)d_in[1];
    const float* W    = (const float*)d_in[3];
    const float* proj = (const float*)d_in[4];
    float*       out  = (float*)d_out;

    char* ws = (char*)d_ws;
    unsigned short* Ahi    = (unsigned short*)(ws + 0);
    unsigned short* AloF   = (unsigned short*)(ws + 16777216);
    unsigned short* Ghi    = (unsigned short*)(ws + 33554432);
    unsigned short* Glo    = (unsigned short*)(ws + 50331648);
    float*          scores = (float*)(ws + 67108864);
    int*            pidx   = (int*)(ws + 67174400);
    unsigned short* selact = (unsigned short*)(ws + 67182592);
    unsigned short* PselT  = (unsigned short*)(ws + 75571200);
    unsigned short* Cbf    = (unsigned short*)(ws + 79765504);
    const bool big = ws_size >= 146874368ull;

    hipMemsetAsync(scores, 0, B_ * P_ * sizeof(float), stream);

    prep_kernel<<<dim3(1024 + P_), 256, 0, stream>>>(act, W, idx, Ahi, AloF, Ghi, Glo);

    if (big) {
        gemm1_score<true><<<dim3(2048), 256, 0, stream>>>(Ahi, AloF, Ghi, Glo, scores, Cbf);
        topk_kernel<<<dim3(B_), 1024, 0, stream>>>(scores, pidx);
        gathers_kernel<<<dim3(2048 + 512), 256, 0, stream>>>(Cbf, proj, pidx, selact, PselT, 0);
    } else {
        gemm1_score<false><<<dim3(2048), 256, 0, stream>>>(Ahi, AloF, Ghi, Glo, scores, nullptr);
        topk_kernel<<<dim3(B_), 1024, 0, stream>>>(scores, pidx);
        gemm1b_selact<<<dim3(KSEL_ / 128, S_ / 128, B_), 256, 0, stream>>>(
            Ahi, AloF, Ghi, Glo, pidx, selact);
        gathers_kernel<<<dim3(512), 256, 0, stream>>>(Cbf, proj, pidx, selact, PselT, 2048);
    }
    gemm2_mfma<<<dim3(D_ / 128, S_ / 128, B_), 256, 0, stream>>>(selact, PselT, out);
}

// Round 8
// 346.815 us; speedup vs baseline: 1.1927x; 1.0167x over previous
//
#include <hip/hip_runtime.h>
#include <hip/hip_bf16.h>
#include <math.h>

#define B_    8
#define S_    2048
#define KIN_  512
#define NIN_  4096
#define P_    2048
#define D_    1024
#define KSEL_ 256

typedef __attribute__((ext_vector_type(8))) short short8;
typedef __attribute__((ext_vector_type(4))) float f32x4;

__device__ __forceinline__ unsigned short f2bf(float f) {
    unsigned u = __float_as_uint(f);
    unsigned r = (u + 0x7fffu + ((u >> 16) & 1u)) >> 16;
    return (unsigned short)r;
}
__device__ __forceinline__ float bf2f(unsigned short h) {
    return __uint_as_float(((unsigned)h) << 16);
}
__device__ __forceinline__ float gelu_exact(float x) {
    return 0.5f * x * (1.0f + erff(x * 0.70710678118654752f));
}
__device__ __forceinline__ void gl2lds16(const void* g, void* l) {
    __builtin_amdgcn_global_load_lds(
        (const __attribute__((address_space(1))) unsigned int*)g,
        (__attribute__((address_space(3))) unsigned int*)l, 16, 0, 0);
}

// ---------------------------------------------------------------------------
// AloF fragment-swizzled layout (16 MB):
//   AloF[b][kb][sb][lane][8]: element (s,k) at b*1048576 + (k>>5)*65536
//       + (s>>4)*512 + (((k>>3)&3)*16 + (s&15))*8 + (k&7)
// A 16-row x 32-k MFMA fragment block is a contiguous 1KB chunk -> one
// coalesced global_load_dwordx4 per lane, straight into the MFMA operand.
// Ahi/Ghi/Glo stay row-major (staged via global_load_lds in gemm1).
// ---------------------------------------------------------------------------

// ---------------------------------------------------------------------------
// prep: blocks [0,1024): split A fp32 -> Ahi (row-major bf16) + AloF
//       blocks [1024,3072): one W row per block. Stage the 16KB row in LDS
//       (coalesced float4) + all 8 batches' idx (16KB); each wave gathers
//       from LDS and writes 2 batches' (Ghi,Glo) rows.
//       blocks [3072,3080): zero the scores buffer (folds the memset
//       dispatch into prep; prep always precedes gemm1's atomics).
// ---------------------------------------------------------------------------
__global__ __launch_bounds__(256) void prep_kernel(
        const float* __restrict__ A, const float* __restrict__ W,
        const int* __restrict__ idx,
        unsigned short* __restrict__ Ahi, unsigned short* __restrict__ AloF,
        unsigned short* __restrict__ Ghi, unsigned short* __restrict__ Glo,
        float* __restrict__ scores) {
    __shared__ float wrow_s[NIN_];      // 16KB
    __shared__ int   ibs8[B_ * KIN_];   // 16KB
    int id = blockIdx.x;
    int t  = threadIdx.x;
    if (id < 1024) {
        int b = id >> 7, rb = id & 127;
        int l = t & 63, wv = t >> 6;
        int lr = l & 15, quad = l >> 4;
        const float* src = A + ((size_t)(b * S_ + rb * 16 + lr)) * KIN_ + quad * 8;
        unsigned short* dh = Ahi + ((size_t)(b * S_ + rb * 16 + lr)) * KIN_ + quad * 8;
        unsigned short* dl = AloF + (size_t)b * 1048576 + (size_t)rb * 512 + (size_t)l * 8;
        for (int kb = wv; kb < 16; kb += 4) {
            float4 v0 = *(const float4*)(src + kb * 32);
            float4 v1 = *(const float4*)(src + kb * 32 + 4);
            float vv[8] = {v0.x, v0.y, v0.z, v0.w, v1.x, v1.y, v1.z, v1.w};
            short8 h8, l8;
#pragma unroll
            for (int jj = 0; jj < 8; jj++) {
                unsigned short h = f2bf(vv[jj]);
                h8[jj] = (short)h;
                l8[jj] = (short)f2bf(vv[jj] - bf2f(h));
            }
            *(short8*)(dh + kb * 32) = h8;
            *(short8*)(dl + (size_t)kb * 65536) = l8;
        }
    } else if (id < 3072) {
        int p = id - 1024;              // 0..2047: one W row, all 8 batches
        const float* wrow = W + (size_t)p * NIN_;
#pragma unroll
        for (int i = 0; i < 4; i++)     // 4096 floats = 1024 float4
            *(float4*)(wrow_s + (t + i * 256) * 4) =
                *(const float4*)(wrow + (t + i * 256) * 4);
#pragma unroll
        for (int i = 0; i < 16; i++)    // 8*512 ints, idx is b-major flat
            ibs8[t + i * 256] = idx[t + i * 256];
        __syncthreads();
        int wv = t >> 6, tt = t & 63;
#pragma unroll
        for (int bi = 0; bi < 2; ++bi) {
            int b = wv * 2 + bi;
            size_t o = ((size_t)b * P_ + p) * KIN_;
            const int* ib = ibs8 + b * KIN_;
            short8 h8, l8;
#pragma unroll
            for (int e = 0; e < 8; e++) {
                float v = wrow_s[ib[tt * 8 + e]];
                unsigned short h = f2bf(v);
                h8[e] = (short)h;
                l8[e] = (short)f2bf(v - bf2f(h));
            }
            *(short8*)(Ghi + o + tt * 8) = h8;
            *(short8*)(Glo + o + tt * 8) = l8;
        }
    } else {
        int z = id - 3072;              // 0..7: zero scores[z*2048 .. +2048)
        float4 zero = {0.f, 0.f, 0.f, 0.f};
        *(float4*)(scores + z * 2048 + t * 8)     = zero;
        *(float4*)(scores + z * 2048 + t * 8 + 4) = zero;
    }
}

// ---------------------------------------------------------------------------
// gemm1_score: x = A*G^T (3-term split bf16 MFMA), scores += sum_s gelu(x).
// Optionally (STORE_C) writes bf16 gelu(x) to C [b][s][p].
// 128x128 tile, BK=32. LDS stages Ahi/Ghi/Glo (2 x 24KB dbuf -> 48KB,
// 3 blocks/CU at ~148 total regs); AloF fragments loaded direct
// global->reg at iteration top — issued BEFORE the vmcnt+barrier, their
// latency hides under the barrier drain (R7 lesson: prefetching them a
// full iteration early is pure overhead, the drain already covers them).
// Source+read XOR swizzle kills the ds_read_b128 bank conflicts; epilogue
// tile padded to 136-short rows. vmcnt(10) = drains stage(it); keeps
// alc(4) + stage(it+1)(6) in flight.
// Block swizzle: 4x4 (p,s)-tile clusters pinned to one XCD.
// NOTE (R2 lesson): do NOT raise min-waves to 4 — 64 arch VGPRs starve the
// direct-load pipeline. NOTE (R6 lesson): the 256²/8-wave deep-pipeline port
// collapses to 1 block/CU (acc=128 AGPR) and loses; don't retry without a
// fundamentally smaller accumulator.
// ---------------------------------------------------------------------------
template <bool STORE_C>
__global__ __launch_bounds__(256, 3) void gemm1_score(
        const unsigned short* __restrict__ Ahi, const unsigned short* __restrict__ AloF,
        const unsigned short* __restrict__ Ghi, const unsigned short* __restrict__ Glo,
        float* __restrict__ scores, unsigned short* __restrict__ C) {
    __shared__ __align__(16) unsigned short lds[24576];  // 2 x 24KB buffers

    // --- XCD cluster swizzle ---
    int d    = blockIdx.x;             // 0..2047
    int xcd  = d & 7;
    int slot = d >> 3;                 // 0..255
    int c    = (slot >> 4) * 8 + xcd;  // cluster 0..127
    int j    = slot & 15;              // position in 4x4 cluster
    int b    = c >> 4;
    int rc   = c & 15;
    int p0   = ((rc & 3) * 4 + (j & 3)) * 128;
    int s0   = ((rc >> 2) * 4 + (j >> 2)) * 128;

    const int t  = threadIdx.x;
    const int w = t >> 6, l = t & 63;
    const int wm = w & 1, wn = w >> 1;
    const int lr = l & 15, quad = l >> 4;

    const int srow = t >> 2;
    const int koff = ((t & 3) ^ ((t >> 3) & 3)) * 8;   // source-side swizzle
    const size_t baseA = ((size_t)(b * S_ + s0)) * KIN_;
    const size_t baseG = ((size_t)(b * P_ + p0)) * KIN_;
    const unsigned short* pA0 = Ahi + baseA + (size_t)srow * KIN_ + koff;
    const unsigned short* pA1 = pA0 + (size_t)64 * KIN_;
    const unsigned short* pG0 = Ghi + baseG + (size_t)srow * KIN_ + koff;
    const unsigned short* pG1 = pG0 + (size_t)64 * KIN_;
    const unsigned short* pH0 = Glo + baseG + (size_t)srow * KIN_ + koff;
    const unsigned short* pH1 = pH0 + (size_t)64 * KIN_;
    const unsigned short* alB = AloF + (size_t)b * 1048576
                              + (size_t)((s0 >> 4) + wm * 4) * 512 + (size_t)l * 8;
    char* lb = (char*)lds + w * 1024;

    int ra[4], rg[4];
#pragma unroll
    for (int i = 0; i < 4; i++) {
        int rowa = wm * 64 + i * 16 + lr;
        int rowg = wn * 64 + i * 16 + lr;
        ra[i] = rowa * 32 + (quad ^ ((rowa >> 1) & 3)) * 8;
        rg[i] = rowg * 32 + (quad ^ ((rowg >> 1) & 3)) * 8;
    }

    f32x4 acc[4][4];
#pragma unroll
    for (int i = 0; i < 4; i++)
#pragma unroll
        for (int jj = 0; jj < 4; jj++) acc[i][jj] = (f32x4){0.f, 0.f, 0.f, 0.f};

    auto issue = [&](int k0, int buf) {
        char* dst = lb + buf * 24576;
        gl2lds16(pA0 + k0, dst + 0);
        gl2lds16(pA1 + k0, dst + 4096);
        gl2lds16(pG0 + k0, dst + 8192);
        gl2lds16(pG1 + k0, dst + 12288);
        gl2lds16(pH0 + k0, dst + 16384);
        gl2lds16(pH1 + k0, dst + 20480);
    };

    issue(0, 0);
    for (int it = 0; it < KIN_ / 32; ++it) {
        // Alo fragments for this K-step, direct from global (coalesced 1KB);
        // issued before the barrier drain, which hides their latency.
        short8 alc[4];
#pragma unroll
        for (int mt = 0; mt < 4; mt++)
            alc[mt] = *(const short8*)(alB + (size_t)it * 65536 + mt * 512);
        if (it + 1 < KIN_ / 32) {
            issue((it + 1) * 32, (it + 1) & 1);
            // outstanding: staging(it)[6] + alc(it)[4] + staging(it+1)[6]
            asm volatile("s_waitcnt vmcnt(10)\n\ts_barrier" ::: "memory");
        } else {
            asm volatile("s_waitcnt vmcnt(0)\n\ts_barrier" ::: "memory");
        }
        const unsigned short* Lb = lds + (it & 1) * 12288;

        short8 gh[4], gl8[4];
#pragma unroll
        for (int i = 0; i < 4; i++) {
            gh[i]  = *(const short8*)(Lb + 4096 + rg[i]);
            gl8[i] = *(const short8*)(Lb + 8192 + rg[i]);
        }
#pragma unroll
        for (int mt = 0; mt < 4; mt++) {
            short8 ah = *(const short8*)(Lb + ra[mt]);
#pragma unroll
            for (int nt = 0; nt < 4; nt++) {
                acc[mt][nt] = __builtin_amdgcn_mfma_f32_16x16x32_bf16(ah,      gh[nt],  acc[mt][nt], 0, 0, 0);
                acc[mt][nt] = __builtin_amdgcn_mfma_f32_16x16x32_bf16(ah,      gl8[nt], acc[mt][nt], 0, 0, 0);
                acc[mt][nt] = __builtin_amdgcn_mfma_f32_16x16x32_bf16(alc[mt], gh[nt],  acc[mt][nt], 0, 0, 0);
            }
        }
        asm volatile("s_barrier" ::: "memory");
    }

    // Epilogue: gelu, per-column score sums, optional bf16 C tile store
    float colsum[4] = {0.f, 0.f, 0.f, 0.f};
#pragma unroll
    for (int mt = 0; mt < 4; mt++)
#pragma unroll
        for (int nt = 0; nt < 4; nt++)
#pragma unroll
            for (int r = 0; r < 4; r++) {
                float g = gelu_exact(acc[mt][nt][r]);
                colsum[nt] += g;
                acc[mt][nt][r] = g;
            }
#pragma unroll
    for (int nt = 0; nt < 4; nt++) {
        colsum[nt] += __shfl_xor(colsum[nt], 16);
        colsum[nt] += __shfl_xor(colsum[nt], 32);
    }
    if (quad == 0) {
#pragma unroll
        for (int nt = 0; nt < 4; nt++)
            atomicAdd(&scores[b * P_ + p0 + wn * 64 + nt * 16 + lr], colsum[nt]);
    }

    if (STORE_C) {
        // padded tile: 136-short rows (272B, 16B-aligned) -> banks spread
#pragma unroll
        for (int mt = 0; mt < 4; mt++)
#pragma unroll
            for (int nt = 0; nt < 4; nt++)
#pragma unroll
                for (int r = 0; r < 4; r++) {
                    int row = wm * 64 + mt * 16 + quad * 4 + r;
                    int col = wn * 64 + nt * 16 + lr;
                    lds[row * 136 + col] = f2bf(acc[mt][nt][r]);
                }
        __syncthreads();
        for (int i = t; i < 2048; i += 256) {
            int row = i >> 4, ch = i & 15;
            uint4 v = *(const uint4*)(lds + row * 136 + ch * 8);
            *(uint4*)(C + ((size_t)(b * S_ + s0 + row)) * P_ + p0 + ch * 8) = v;
        }
    }
}

// ---------------------------------------------------------------------------
// top-256 of 2048 scores per batch (bitonic, desc, tie: low idx).
// Selected indices re-sorted ascending (set-invariant for the output).
// ---------------------------------------------------------------------------
__global__ __launch_bounds__(1024) void topk_kernel(const float* __restrict__ scores,
                                                    int* __restrict__ pidx) {
    __shared__ float v[2048];
    __shared__ int   ix[2048];
    int b = blockIdx.x;
    int t = threadIdx.x;
    for (int i = t; i < 2048; i += 1024) { v[i] = scores[b * 2048 + i]; ix[i] = i; }
    __syncthreads();
    for (int k = 2; k <= 2048; k <<= 1) {
        for (int j = k >> 1; j > 0; j >>= 1) {
            for (int i = t; i < 2048; i += 1024) {
                int o = i ^ j;
                if (o > i) {
                    bool desc = ((i & k) == 0);
                    float va = v[i], vb = v[o];
                    int ia = ix[i], ib = ix[o];
                    bool b_first = (vb > va) || (vb == va && ib < ia);
                    if (desc == b_first) { v[i] = vb; v[o] = va; ix[i] = ib; ix[o] = ia; }
                }
            }
            __syncthreads();
        }
    }
    // ascending re-sort of the selected 256 indices (set-invariant)
    for (int k = 2; k <= 256; k <<= 1) {
        for (int j = k >> 1; j > 0; j >>= 1) {
            if (t < 256) {
                int i = t, o = i ^ j;
                if (o > i) {
                    bool asc = ((i & k) == 0);
                    int a = ix[i], c2 = ix[o];
                    if ((a > c2) == asc) { ix[i] = c2; ix[o] = a; }
                }
            }
            __syncthreads();
        }
    }
    if (t < KSEL_) pidx[b * KSEL_ + t] = ix[t];
}

// ---------------------------------------------------------------------------
// gathers: id in [0,2048): selact[b][s][t] = C[b][s][pidx[b][t]]
//          id in [2048,2560): PselT[b][d][k] = bf16(proj[pidx[b][k]][d])
// ---------------------------------------------------------------------------
__global__ __launch_bounds__(256) void gathers_kernel(
        const unsigned short* __restrict__ C, const float* __restrict__ proj,
        const int* __restrict__ pidx,
        unsigned short* __restrict__ selact, unsigned short* __restrict__ PselT,
        int base) {
    __shared__ int pj[256];
    __shared__ unsigned short tile[64][65];
    int id = blockIdx.x + base, t = threadIdx.x;
    if (id < 2048) {
        int b = id >> 8;
        pj[t] = pidx[b * KSEL_ + t];
        __syncthreads();
        size_t r0 = (size_t)b * S_ + (id & 255) * 8;
#pragma unroll
        for (int r = 0; r < 8; ++r) {
            size_t row = r0 + r;
            selact[row * KSEL_ + t] = C[row * P_ + pj[t]];
        }
    } else {
        int g = id - 2048;
        int d0 = (g & 15) * 64, k0 = ((g >> 4) & 3) * 64, b = g >> 6;
        int tr = t >> 6;     // 0..3
        int tc = t & 63;
#pragma unroll
        for (int r = 0; r < 16; r++) {
            int kk = r * 4 + tr;
            int prow = pidx[b * KSEL_ + k0 + kk];
            tile[kk][tc] = f2bf(proj[(size_t)prow * D_ + d0 + tc]);
        }
        __syncthreads();
#pragma unroll
        for (int r = 0; r < 16; r++) {
            int dd = r * 4 + tr;
            PselT[((size_t)(b * D_ + d0 + dd)) * KSEL_ + k0 + tc] = tile[tc][dd];
        }
    }
}

// ---------------------------------------------------------------------------
// gemm1b (fallback when ws too small): recompute selected 256 columns.
// Ahi/Ghi/Glo staged (single buffer); AloF direct.
// ---------------------------------------------------------------------------
__global__ __launch_bounds__(256) void gemm1b_selact(
        const unsigned short* __restrict__ Ahi, const unsigned short* __restrict__ AloF,
        const unsigned short* __restrict__ Ghi, const unsigned short* __restrict__ Glo,
        const int* __restrict__ pidx, unsigned short* __restrict__ selact) {
    __shared__ __align__(16) unsigned short lds[16384];

    const int t  = threadIdx.x;
    const int b  = blockIdx.z;
    const int s0 = blockIdx.y * 128;
    const int n0 = blockIdx.x * 128;
    const int w = t >> 6, l = t & 63;
    const int wm = w & 1, wn = w >> 1;
    const int lr = l & 15, quad = l >> 4;

    const int srow = t >> 2;
    const int koff = ((t & 3) ^ ((t >> 3) & 3)) * 8;
    const size_t baseA = ((size_t)(b * S_ + s0)) * KIN_;
    const size_t offA0 = baseA + (size_t)srow * KIN_ + koff;
    const size_t offA1 = offA0 + (size_t)64 * KIN_;
    const int prow0 = pidx[b * KSEL_ + n0 + srow];
    const int prow1 = pidx[b * KSEL_ + n0 + 64 + srow];
    const size_t offG0 = ((size_t)(b * P_ + prow0)) * KIN_ + koff;
    const size_t offG1 = ((size_t)(b * P_ + prow1)) * KIN_ + koff;
    const unsigned short* alB = AloF + (size_t)b * 1048576
                              + (size_t)((s0 >> 4) + wm * 4) * 512 + (size_t)l * 8;
    char* lb = (char*)lds + w * 1024;

    int ra[4], rg[4];
#pragma unroll
    for (int i = 0; i < 4; i++) {
        int rowa = wm * 64 + i * 16 + lr;
        int rowg = wn * 64 + i * 16 + lr;
        ra[i] = rowa * 32 + (quad ^ ((rowa >> 1) & 3)) * 8;
        rg[i] = rowg * 32 + (quad ^ ((rowg >> 1) & 3)) * 8;
    }

    f32x4 acc[4][4];
#pragma unroll
    for (int i = 0; i < 4; i++)
#pragma unroll
        for (int jj = 0; jj < 4; jj++) acc[i][jj] = (f32x4){0.f, 0.f, 0.f, 0.f};

    for (int k0 = 0; k0 < KIN_; k0 += 32) {
        int kb = k0 >> 5;
        gl2lds16(Ahi + offA0 + k0, lb + 0);
        gl2lds16(Ahi + offA1 + k0, lb + 4096);
        gl2lds16(Ghi + offG0 + k0, lb + 8192);
        gl2lds16(Ghi + offG1 + k0, lb + 12288);
        gl2lds16(Glo + offG0 + k0, lb + 16384);
        gl2lds16(Glo + offG1 + k0, lb + 20480);
        short8 alc[4];
#pragma unroll
        for (int i = 0; i < 4; i++)
            alc[i] = *(const short8*)(alB + (size_t)kb * 65536 + i * 512);
        __syncthreads();

        short8 gh[4], gl8[4];
#pragma unroll
        for (int i = 0; i < 4; i++) {
            gh[i]  = *(const short8*)(lds + 4096 + rg[i]);
            gl8[i] = *(const short8*)(lds + 8192 + rg[i]);
        }
#pragma unroll
        for (int mt = 0; mt < 4; mt++) {
            short8 ah = *(const short8*)(lds + ra[mt]);
#pragma unroll
            for (int nt = 0; nt < 4; nt++) {
                acc[mt][nt] = __builtin_amdgcn_mfma_f32_16x16x32_bf16(ah,      gh[nt],  acc[mt][nt], 0, 0, 0);
                acc[mt][nt] = __builtin_amdgcn_mfma_f32_16x16x32_bf16(ah,      gl8[nt], acc[mt][nt], 0, 0, 0);
                acc[mt][nt] = __builtin_amdgcn_mfma_f32_16x16x32_bf16(alc[mt], gh[nt],  acc[mt][nt], 0, 0, 0);
            }
        }
        __syncthreads();
    }

#pragma unroll
    for (int mt = 0; mt < 4; mt++)
#pragma unroll
        for (int nt = 0; nt < 4; nt++)
#pragma unroll
            for (int r = 0; r < 4; r++) {
                int row = wm * 64 + mt * 16 + quad * 4 + r;
                int col = wn * 64 + nt * 16 + lr;
                lds[row * 128 + col] = f2bf(gelu_exact(acc[mt][nt][r]));
            }
    __syncthreads();
    for (int i = t; i < 2048; i += 256) {
        int row = i >> 4, ch = i & 15;
        uint4 v = *(const uint4*)(lds + row * 128 + ch * 8);
        *(uint4*)(selact + ((size_t)(b * S_ + s0 + row)) * KSEL_ + n0 + ch * 8) = v;
    }
}

// ---------------------------------------------------------------------------
// gemm2: out[b][s][d] = sum_k selact[b][s][k] * PselT[b][d][k]  (bf16 MFMA)
// dbuf LDS + raw vmcnt(4)/s_barrier pipeline; XOR source+read swizzle.
// ---------------------------------------------------------------------------
__global__ __launch_bounds__(256) void gemm2_mfma(
        const unsigned short* __restrict__ selact,
        const unsigned short* __restrict__ PselT,
        float* __restrict__ out) {
    __shared__ __align__(16) unsigned short lds[16384];  // 2 x 16KB buffers

    const int t  = threadIdx.x;
    const int b  = blockIdx.z;
    const int s0 = blockIdx.y * 128;
    const int d0 = blockIdx.x * 128;
    const int w = t >> 6, l = t & 63;
    const int wm = w & 1, wn = w >> 1;
    const int lr = l & 15, quad = l >> 4;

    const int srow = t >> 2;
    const int koff = ((t & 3) ^ ((t >> 3) & 3)) * 8;
    const unsigned short* pA0 = selact + ((size_t)(b * S_ + s0 + srow)) * KSEL_ + koff;
    const unsigned short* pA1 = pA0 + (size_t)64 * KSEL_;
    const unsigned short* pB0 = PselT + ((size_t)(b * D_ + d0 + srow)) * KSEL_ + koff;
    const unsigned short* pB1 = pB0 + (size_t)64 * KSEL_;
    char* lb = (char*)lds + w * 1024;

    int ra[4], rg[4];
#pragma unroll
    for (int i = 0; i < 4; i++) {
        int rowa = wm * 64 + i * 16 + lr;
        int rowg = wn * 64 + i * 16 + lr;
        ra[i] = rowa * 32 + (quad ^ ((rowa >> 1) & 3)) * 8;
        rg[i] = rowg * 32 + (quad ^ ((rowg >> 1) & 3)) * 8;
    }

    f32x4 acc[4][4];
#pragma unroll
    for (int i = 0; i < 4; i++)
#pragma unroll
        for (int jj = 0; jj < 4; jj++) acc[i][jj] = (f32x4){0.f, 0.f, 0.f, 0.f};

    auto issue = [&](int k0, int buf) {
        char* dst = lb + buf * 16384;
        gl2lds16(pA0 + k0, dst + 0);
        gl2lds16(pA1 + k0, dst + 4096);
        gl2lds16(pB0 + k0, dst + 8192);
        gl2lds16(pB1 + k0, dst + 12288);
    };

    issue(0, 0);
    for (int it = 0; it < KSEL_ / 32; ++it) {
        if (it + 1 < KSEL_ / 32) {
            issue((it + 1) * 32, (it + 1) & 1);
            asm volatile("s_waitcnt vmcnt(4)\n\ts_barrier" ::: "memory");
        } else {
            asm volatile("s_waitcnt vmcnt(0)\n\ts_barrier" ::: "memory");
        }
        const unsigned short* Lb = lds + (it & 1) * 8192;

        short8 af[4], bf[4];
#pragma unroll
        for (int i = 0; i < 4; i++) {
            af[i] = *(const short8*)(Lb + ra[i]);
            bf[i] = *(const short8*)(Lb + 4096 + rg[i]);
        }
#pragma unroll
        for (int mt = 0; mt < 4; mt++)
#pragma unroll
            for (int nt = 0; nt < 4; nt++)
                acc[mt][nt] = __builtin_amdgcn_mfma_f32_16x16x32_bf16(af[mt], bf[nt], acc[mt][nt], 0, 0, 0);
        asm volatile("s_barrier" ::: "memory");
    }

#pragma unroll
    for (int mt = 0; mt < 4; mt++)
#pragma unroll
        for (int nt = 0; nt < 4; nt++)
#pragma unroll
            for (int r = 0; r < 4; r++)
                out[((size_t)(b * S_ + s0 + wm * 64 + mt * 16 + quad * 4 + r)) * D_
                    + d0 + wn * 64 + nt * 16 + lr] = acc[mt][nt][r];
}

// ---------------------------------------------------------------------------
// Workspace layout (bytes):
//   Ahi/AloF/Ghi/Glo bf16 @ 0..67108863   (4 x 16,777,216; AloF frag-swizzled)
//   scores fp32           @ 67,108,864    (65,536)
//   pidx   int            @ 67,174,400    (8,192)
//   selact bf16           @ 67,182,592    (8,388,608)
//   PselT  bf16           @ 75,571,200    (4,194,304)      -> 79,765,504 (base)
//   C      bf16 [8][2048][2048] @ 79,765,504 (67,108,864)  -> 146,874,368 (big)
// ---------------------------------------------------------------------------
extern "C" void kernel_launch(void* const* d_in, const int* in_sizes, int n_in,
                              void* d_out, int out_size, void* d_ws, size_t ws_size,
                              hipStream_t stream) {
    (void)in_sizes; (void)n_in; (void)out_size;
    const float* act  = (const float*)d_in[0];
    const int*   idx  = (const int*)d_in[1];
    const float* W    = (const float*)d_in[3];
    const float* proj = (const float*)d_in[4];
    float*       out  = (float*)d_out;

    char* ws = (char*)d_ws;
    unsigned short* Ahi    = (unsigned short*)(ws + 0);
    unsigned short* AloF   = (unsigned short*)(ws + 16777216);
    unsigned short* Ghi    = (unsigned short*)(ws + 33554432);
    unsigned short* Glo    = (unsigned short*)(ws + 50331648);
    float*          scores = (float*)(ws + 67108864);
    int*            pidx   = (int*)(ws + 67174400);
    unsigned short* selact = (unsigned short*)(ws + 67182592);
    unsigned short* PselT  = (unsigned short*)(ws + 75571200);
    unsigned short* Cbf    = (unsigned short*)(ws + 79765504);
    const bool big = ws_size >= 146874368ull;

    prep_kernel<<<dim3(1024 + P_ + 8), 256, 0, stream>>>(act, W, idx, Ahi, AloF, Ghi, Glo, scores);

    if (big) {
        gemm1_score<true><<<dim3(2048), 256, 0, stream>>>(Ahi, AloF, Ghi, Glo, scores, Cbf);
        topk_kernel<<<dim3(B_), 1024, 0, stream>>>(scores, pidx);
        gathers_kernel<<<dim3(2048 + 512), 256, 0, stream>>>(Cbf, proj, pidx, selact, PselT, 0);
    } else {
        gemm1_score<false><<<dim3(2048), 256, 0, stream>>>(Ahi, AloF, Ghi, Glo, scores, nullptr);
        topk_kernel<<<dim3(B_), 1024, 0, stream>>>(scores, pidx);
        gemm1b_selact<<<dim3(KSEL_ / 128, S_ / 128, B_), 256, 0, stream>>>(
            Ahi, AloF, Ghi, Glo, pidx, selact);
        gathers_kernel<<<dim3(512), 256, 0, stream>>>(Cbf, proj, pidx, selact, PselT, 2048);
    }
    gemm2_mfma<<<dim3(D_ / 128, S_ / 128, B_), 256, 0, stream>>>(selact, PselT, out);
}